// Round 11
// baseline (2045.547 us; speedup 1.0000x reference)
//
#include <hip/hip_runtime.h>

#define Hn 2048
#define Bn 8
#define Tn 2048
#define Cn 16
#define NCn (Tn / Cn)     // 128 chunks
#define M2n (NCn * Bn)    // 1024 scan rows

using f32x4 = __attribute__((ext_vector_type(4))) float;
using u32x4 = __attribute__((ext_vector_type(4))) unsigned int;
using us4   = __attribute__((ext_vector_type(4))) unsigned short;
using bf8   = __attribute__((ext_vector_type(8))) short;
using f4    = __attribute__((ext_vector_type(4))) float;

#define GLOAD16(g, l) __builtin_amdgcn_global_load_lds(                      \
    (const __attribute__((address_space(1))) void*)(g),                      \
    (__attribute__((address_space(3))) void*)(l), 16, 0, 0)

__device__ __forceinline__ unsigned short f2bf(float f) {
    unsigned u = __builtin_bit_cast(unsigned, f);
    u = u + 0x7fffu + ((u >> 16) & 1u);
    return (unsigned short)(u >> 16);
}
__device__ __forceinline__ float bf2f(unsigned short h) {
    unsigned u = ((unsigned)h) << 16;
    return __builtin_bit_cast(float, u);
}
__device__ __forceinline__ void split2f(float v, unsigned short& a, unsigned short& b) {
    a = f2bf(v);
    b = f2bf(v - bf2f(a));
}

// ---------------------------------------------------------------------------
// Mega-prep kernel (single launch, block-range dispatch):
//  [0, 4096)            : A 2-way split
//  [4096, 5120)         : B^T 2-way split (transpose)
//  [5120]               : reset canonicalize + counting sort
//  [5121, 5121+32768)   : X 2-way split (only when prex grid launched)
// ---------------------------------------------------------------------------
__global__ __launch_bounds__(256) void k_prep(const float* __restrict__ A,
                                              unsigned short* __restrict__ a1,
                                              unsigned short* __restrict__ a2,
                                              const float* __restrict__ Bm,
                                              unsigned short* __restrict__ b1,
                                              unsigned short* __restrict__ b2,
                                              const float* __restrict__ X,
                                              unsigned short* __restrict__ x1,
                                              unsigned short* __restrict__ x2,
                                              const unsigned int* __restrict__ rin,
                                              unsigned char* __restrict__ r8,
                                              int* __restrict__ cut,
                                              int* __restrict__ firstReset,
                                              int* __restrict__ anyUncut,
                                              int* __restrict__ perm,
                                              int* __restrict__ iperm,
                                              int* __restrict__ counts) {
    const int bid = blockIdx.x;
    if (bid < 4096) {
        size_t i = ((size_t)bid * 256 + threadIdx.x) * 4;
        f32x4 v = *(const f32x4*)&A[i];
        us4 h1, h2;
#pragma unroll
        for (int e = 0; e < 4; e++) {
            unsigned short p, r;
            split2f(v[e], p, r);
            h1[e] = p; h2[e] = r;
        }
        *(us4*)&a1[i] = h1; *(us4*)&a2[i] = h2;
        return;
    }
    if (bid < 5120) {
        __shared__ float tile[64][65];
        int t = bid - 4096;
        const int k0 = (t >> 5) * 64, n0 = (t & 31) * 64;
        const int c = threadIdx.x & 63, r4 = threadIdx.x >> 6;
#pragma unroll
        for (int i = 0; i < 16; i++) {
            int r = r4 * 16 + i;
            tile[r][c] = Bm[(size_t)(k0 + r) * Hn + n0 + c];
        }
        __syncthreads();
#pragma unroll
        for (int i = 0; i < 16; i++) {
            int r = r4 * 16 + i;
            float v = tile[c][r];
            unsigned short p, q;
            split2f(v, p, q);
            b1[(size_t)(n0 + r) * Hn + k0 + c] = p;
            b2[(size_t)(n0 + r) * Hn + k0 + c] = q;
        }
        return;
    }
    if (bid == 5120) {
        __shared__ int s_badInt, s_badFloat;
        __shared__ int hist[17], off[18], cur[17];
        if (threadIdx.x == 0) { s_badInt = 0; s_badFloat = 0; *anyUncut = 0; }
        if (threadIdx.x < 17) hist[threadIdx.x] = 0;
        __syncthreads();
        int badI = 0, badF = 0;
        for (int i = threadIdx.x; i < 4096; i += 256) {
            unsigned int v = rin[i];
            if (v > 1u) badI = 1;
            if (v != 0u && v != 0x3f800000u) badF = 1;
        }
        if (badI) atomicOr(&s_badInt, 1);
        if (badF) atomicOr(&s_badFloat, 1);
        __syncthreads();
        const int fmt = (!s_badInt) ? 0 : ((!s_badFloat) ? 1 : 2);
        const unsigned char* rb = (const unsigned char*)rin;
        const float* rf = (const float*)rin;
        for (int i = threadIdx.x; i < Bn * Tn; i += 256) {
            unsigned char v;
            if (fmt == 0)      v = (unsigned char)(rin[i] != 0u);
            else if (fmt == 1) v = (unsigned char)(rf[i] != 0.0f);
            else               v = (unsigned char)(rb[i] != 0);
            r8[i] = v;
        }
        __syncthreads();
        int anyU = 0;
        for (int m = threadIdx.x; m < M2n; m += 256) {
            int c = m / Bn, b = m % Bn;
            int fr = Cn;
            for (int j = 0; j < Cn; j++) {
                if (r8[b * Tn + c * Cn + j]) { fr = j; break; }
            }
            firstReset[m] = fr;
            int ct = (fr < Cn);
            cut[m] = ct;
            if (!ct && c < NCn - 1) anyU = 1;
            atomicAdd(&hist[fr], 1);
        }
        if (anyU) atomicOr(anyUncut, 1);
        __syncthreads();
        if (threadIdx.x == 0) {
            off[16] = 0;
            for (int v = 15; v >= 0; v--) off[v] = off[v + 1] + hist[v + 1];
            for (int v = 0; v < 17; v++) cur[v] = (v == 16) ? 0 : off[v];
            for (int j = 0; j < 16; j++) counts[j] = off[j];
        }
        __syncthreads();
        for (int m = threadIdx.x; m < M2n; m += 256) {
            int fr = firstReset[m];
            int pos = atomicAdd(&cur[fr], 1);
            perm[pos] = m;
            iperm[m] = pos;
        }
        return;
    }
    {
        size_t i = ((size_t)(bid - 5121) * 256 + threadIdx.x) * 4;
        f32x4 v = *(const f32x4*)&X[i];
        us4 h1, h2;
#pragma unroll
        for (int e = 0; e < 4; e++) {
            unsigned short p, r;
            split2f(v[e], p, r);
            h1[e] = p; h2[e] = r;
        }
        *(us4*)&x1[i] = h1; *(us4*)&x2[i] = h2;
    }
}

// ---------------------------------------------------------------------------
// Phase-1 GEMM: Out[m,n] = sum_k X[m,k]*Bt[n,k], 3 products.
// 256x128 tile, 512 threads (8 waves, 4m x 2n), FM=FN=4, BK=32, granule
// swizzle (conflict-free), global_load_lds staging, simple 2-barrier loop
// (R6/R8-proven). Fused step0 for t%16==0 rows.
// ---------------------------------------------------------------------------
template<int PREX>
__global__ __launch_bounds__(512) void k_gemm_p1(const unsigned short* __restrict__ X0,
                                                 const unsigned short* __restrict__ X1,
                                                 const unsigned short* __restrict__ B0,
                                                 const unsigned short* __restrict__ B1,
                                                 const float* __restrict__ Xf,
                                                 float* __restrict__ Out,
                                                 unsigned short* __restrict__ S0,
                                                 unsigned short* __restrict__ S1) {
    constexpr int BM = 256, BN = 128, LW = 32;
    __shared__ unsigned short ldsA[2 * BM * LW];   // 32 KB
    __shared__ unsigned short ldsB[2 * BN * LW];   // 16 KB
    const int tid = threadIdx.x;
    const int lane = tid & 63;
    const int wv = tid >> 6;
    const int wm = wv >> 1, wn = wv & 1;
    const int n0 = blockIdx.x * BN;
    const int m0 = blockIdx.y * BM;

    f4 acc[4][4];
#pragma unroll
    for (int fm = 0; fm < 4; fm++)
#pragma unroll
        for (int fn = 0; fn < 4; fn++) acc[fm][fn] = (f4){0.f, 0.f, 0.f, 0.f};

    const unsigned short* gA[4];
    unsigned short* lA[4];
    const float* gX[2];
    unsigned short* lX[2];
    const unsigned short* gB[2];
    unsigned short* lB[2];
    if constexpr (PREX) {
#pragma unroll
        for (int q = 0; q < 4; q++) {
            int u = tid + q * 512;                 // 2048 granules (16B each)
            int sp = u >> 10, row = (u >> 2) & 255, slot = u & 3;
            int g = slot ^ ((row >> 1) & 3);       // swizzled source granule
            gA[q] = (sp ? X1 : X0) + (size_t)(m0 + row) * Hn + g * 8;
            lA[q] = &ldsA[u * 8];                  // linear LDS dest
        }
    } else {
#pragma unroll
        for (int q = 0; q < 2; q++) {
            int u = tid + q * 512;                 // 1024 items (row x granule)
            int row = u >> 2, slot = u & 3;
            int s = slot ^ ((row >> 1) & 3);       // swizzled LDS slot
            gX[q] = Xf + (size_t)(m0 + row) * Hn + slot * 8;
            lX[q] = &ldsA[row * LW + s * 8];       // hi plane; lo at +BM*LW
        }
    }
#pragma unroll
    for (int q = 0; q < 2; q++) {
        int u = tid + q * 512;                     // 1024 granules
        int sp = u >> 9, row = (u >> 2) & 127, slot = u & 3;
        int g = slot ^ ((row >> 1) & 3);
        gB[q] = (sp ? B1 : B0) + (size_t)(n0 + row) * Hn + g * 8;
        lB[q] = &ldsB[u * 8];
    }
    const int sl = (lane >> 4) ^ ((lane >> 1) & 3);   // read-side slot per lane
    const int pa[3] = {0, 0, 1};
    const int pb[3] = {0, 1, 0};

    for (int k0 = 0; k0 < Hn; k0 += 32) {
        if constexpr (PREX) {
#pragma unroll
            for (int q = 0; q < 4; q++) {
                GLOAD16(gA[q], lA[q]);
                gA[q] += 32;
            }
        } else {
#pragma unroll
            for (int q = 0; q < 2; q++) {
                f32x4 va = *(const f32x4*)gX[q];
                f32x4 vb = *(const f32x4*)(gX[q] + 4);
                gX[q] += 32;
                us4 h1a, h2a, h1b, h2b;
#pragma unroll
                for (int e = 0; e < 4; e++) {
                    unsigned short p, r;
                    split2f(va[e], p, r); h1a[e] = p; h2a[e] = r;
                    split2f(vb[e], p, r); h1b[e] = p; h2b[e] = r;
                }
                *(us4*)lX[q] = h1a;
                *(us4*)(lX[q] + 4) = h1b;
                *(us4*)(lX[q] + BM * LW) = h2a;
                *(us4*)(lX[q] + BM * LW + 4) = h2b;
            }
        }
#pragma unroll
        for (int q = 0; q < 2; q++) {
            GLOAD16(gB[q], lB[q]);
            gB[q] += 32;
        }
        __syncthreads();   // drains vmcnt(0): DMA staging complete

        bf8 af[2][4], bfr[2][4];
#pragma unroll
        for (int sp = 0; sp < 2; sp++)
#pragma unroll
            for (int f = 0; f < 4; f++)
                af[sp][f] = *(const bf8*)&ldsA[(sp * BM + wm * 64 + f * 16 + (lane & 15)) * LW + sl * 8];
#pragma unroll
        for (int sp = 0; sp < 2; sp++)
#pragma unroll
            for (int f = 0; f < 4; f++)
                bfr[sp][f] = *(const bf8*)&ldsB[(sp * BN + wn * 64 + f * 16 + (lane & 15)) * LW + sl * 8];

#pragma unroll
        for (int p = 0; p < 3; p++)
#pragma unroll
            for (int fm = 0; fm < 4; fm++)
#pragma unroll
                for (int fn = 0; fn < 4; fn++)
                    acc[fm][fn] = __builtin_amdgcn_mfma_f32_16x16x32_bf16(
                        af[pa[p]][fm], bfr[pb[p]][fn], acc[fm][fn], 0, 0, 0);
        __syncthreads();   // protect LDS reuse before next stage
    }

    // D mapping: row=(lane>>4)*4+r, col=lane&15. Fused step0 for t%16==0 rows.
#pragma unroll
    for (int fm = 0; fm < 4; fm++)
#pragma unroll
        for (int r = 0; r < 4; r++) {
            int row = m0 + wm * 64 + fm * 16 + (lane >> 4) * 4 + r;
            int bb = row >> 11, t = row & 2047;
            int isC0 = ((t & 15) == 0);
            size_t ob = (size_t)row * Hn;
            size_t sb = (size_t)((t >> 4) * 8 + bb) * Hn;
#pragma unroll
            for (int fn = 0; fn < 4; fn++) {
                int n = n0 + wn * 64 + fn * 16 + (lane & 15);
                float v = acc[fm][fn][r];
                Out[ob + n] = v;
                if (isC0) {
                    unsigned short h1, h2;
                    split2f(v, h1, h2);
                    S0[sb + n] = h1; S1[sb + n] = h2;
                }
            }
        }
}

// ---------------------------------------------------------------------------
// Scan / correction GEMM: 64x64 tile, 256 threads (2x2 waves), FM=FN=2, BK=64.
// A-operand (state rows): DIRECT global->register b128 loads (no LDS round
// trip — each wave's 32 rows are private, LDS staging buys nothing; state is
// L2-warm). B-operand (weight panel, shared): gload_lds + granule swizzle +
// 2-deep double-buffered counted-vmcnt(4) pipeline. LDS 32 KB. setprio
// around MFMA. Grid 512 = 2 blocks/CU.
// PHASE 2: v=(reset?0:acc)+Out; Out=v; split2 -> state.
// PHASE 3: as PHASE 2 (j=15) + carry u at iperm[m+8] + Hin[m+8]; zeroes
//          chunk-0 carry rows (m<8) inline.
// PHASE 4: correction on sorted alive prefix.
// ---------------------------------------------------------------------------
template<int PHASE>
__global__ __launch_bounds__(256) void k_gemm_s(const unsigned short* __restrict__ S0,
                                                const unsigned short* __restrict__ S1,
                                                const unsigned short* __restrict__ W0,
                                                const unsigned short* __restrict__ W1,
                                                float* __restrict__ Out,
                                                unsigned short* __restrict__ O0,
                                                unsigned short* __restrict__ O1,
                                                const unsigned char* __restrict__ r8v,
                                                const int* __restrict__ perm,
                                                const int* __restrict__ iperm,
                                                const int* __restrict__ counts,
                                                unsigned short* __restrict__ U0,
                                                unsigned short* __restrict__ U1,
                                                float* __restrict__ Hin,
                                                int j) {
    constexpr int BM = 64, BN = 64, BK = 64;
    constexpr int TSZ = 2 * BN * BK;               // 8192 shorts per B buffer
    constexpr int NT = Hn / BK;                    // 32 k-tiles
    __shared__ unsigned short ldsB[2 * TSZ];       // 32 KB (2 bufs)
    const int tid = threadIdx.x;
    const int lane = tid & 63;
    const int wv = tid >> 6;
    const int wm = wv >> 1, wn = wv & 1;
    const int n0 = blockIdx.x * BN;
    const int m0 = blockIdx.y * BM;

    int cnt = 0;
    if constexpr (PHASE == 4) {
        cnt = counts[j];
        if (m0 >= cnt) return;
    }

    f4 acc[2][2];
#pragma unroll
    for (int fm = 0; fm < 2; fm++)
#pragma unroll
        for (int fn = 0; fn < 2; fn++) acc[fm][fn] = (f4){0.f, 0.f, 0.f, 0.f};

    // B staging (4 gload_lds per stage)
    const unsigned short* gB[4];
    unsigned short* lB[4];
#pragma unroll
    for (int q = 0; q < 4; q++) {
        int u = tid + q * 256;                     // 1024 granules
        int sp = u >> 9, row = (u >> 3) & 63, s = u & 7;
        int g = s ^ (row & 7);                     // swizzled source granule
        gB[q] = (sp ? W1 : W0) + (size_t)(n0 + row) * Hn + g * 8;
        lB[q] = &ldsB[u * 8];
    }
    // A direct-load fragment pointers: [h][sp][f]
    const unsigned short* gAf[2][2][2];
#pragma unroll
    for (int h = 0; h < 2; h++)
#pragma unroll
        for (int sp = 0; sp < 2; sp++)
#pragma unroll
            for (int f = 0; f < 2; f++)
                gAf[h][sp][f] = (sp ? S1 : S0)
                    + (size_t)(m0 + wm * 32 + f * 16 + (lane & 15)) * Hn
                    + h * 32 + (lane >> 4) * 8;

    const int pa[3] = {0, 0, 1};
    const int pb[3] = {0, 1, 0};

#define STAGE_B(bsel)                                                        \
    {                                                                        \
        const int boff_ = (bsel) * TSZ;                                      \
        _Pragma("unroll")                                                    \
        for (int q = 0; q < 4; q++) {                                        \
            GLOAD16(gB[q], lB[q] + boff_);                                   \
            gB[q] += BK;                                                     \
        }                                                                    \
    }

    // prologue: stage B tiles 0 and 1
    STAGE_B(0);
    STAGE_B(1);

    for (int t = 0; t < NT; t++) {
        if (t == NT - 1) { asm volatile("s_waitcnt vmcnt(0)" ::: "memory"); }
        else             { asm volatile("s_waitcnt vmcnt(4)" ::: "memory"); }
        __builtin_amdgcn_sched_barrier(0);
        __builtin_amdgcn_s_barrier();

        const unsigned short* curB = &ldsB[(t & 1) * TSZ];
        bf8 af[2][2][2], bfr[2][2][2];             // [h][sp][f]
#pragma unroll
        for (int h = 0; h < 2; h++) {
            const int slh = ((h * 4) + (lane >> 4)) ^ (lane & 7);
#pragma unroll
            for (int sp = 0; sp < 2; sp++)
#pragma unroll
                for (int f = 0; f < 2; f++)
                    bfr[h][sp][f] = *(const bf8*)&curB[(sp * BN + wn * 32 + f * 16 + (lane & 15)) * BK + slh * 8];
        }
        // A fragments: direct global->register (compiler-managed waits)
#pragma unroll
        for (int h = 0; h < 2; h++)
#pragma unroll
            for (int sp = 0; sp < 2; sp++)
#pragma unroll
                for (int f = 0; f < 2; f++) {
                    af[h][sp][f] = *(const bf8*)gAf[h][sp][f];
                    gAf[h][sp][f] += BK;
                }
        asm volatile("s_waitcnt lgkmcnt(0)" ::: "memory");
        __builtin_amdgcn_sched_barrier(0);
        __builtin_amdgcn_s_barrier();

        if (t + 2 < NT) STAGE_B(t & 1);
        __builtin_amdgcn_sched_barrier(0);

        __builtin_amdgcn_s_setprio(1);
#pragma unroll
        for (int h = 0; h < 2; h++)
#pragma unroll
            for (int p = 0; p < 3; p++)
#pragma unroll
                for (int fm = 0; fm < 2; fm++)
#pragma unroll
                    for (int fn = 0; fn < 2; fn++)
                        acc[fm][fn] = __builtin_amdgcn_mfma_f32_16x16x32_bf16(
                            af[h][pa[p]][fm], bfr[h][pb[p]][fn], acc[fm][fn], 0, 0, 0);
        __builtin_amdgcn_s_setprio(0);
    }
#undef STAGE_B

    if constexpr (PHASE == 2 || PHASE == 3) {
#pragma unroll
        for (int fm = 0; fm < 2; fm++)
#pragma unroll
            for (int r = 0; r < 4; r++) {
                int m = m0 + wm * 32 + fm * 16 + (lane >> 4) * 4 + r;
                int cch = m >> 3, bb = m & 7;
                int t = cch * Cn + j;
                int rfl = r8v[bb * Tn + t];
                size_t ob = ((size_t)bb * Tn + t) * (size_t)Hn;
                size_t sb = (size_t)m * Hn;
                int carry = 0;
                size_t ub = 0, hb = 0;
                if constexpr (PHASE == 3) {
                    carry = (m < M2n - 8);
                    if (carry) {
                        ub = (size_t)iperm[m + 8] * Hn;
                        hb = (size_t)(m + 8) * Hn;
                    }
                }
#pragma unroll
                for (int fn = 0; fn < 2; fn++) {
                    int n = n0 + wn * 32 + fn * 16 + (lane & 15);
                    float v = (rfl ? 0.0f : acc[fm][fn][r]) + Out[ob + n];
                    Out[ob + n] = v;
                    unsigned short h1, h2;
                    split2f(v, h1, h2);
                    O0[sb + n] = h1; O1[sb + n] = h2;
                    if constexpr (PHASE == 3) {
                        if (carry) {
                            U0[ub + n] = h1; U1[ub + n] = h2;
                            Hin[hb + n] = v;
                        }
                        if (m < 8) {                       // chunk-0 carry = 0
                            size_t zb = (size_t)iperm[m] * Hn;
                            U0[zb + n] = 0; U1[zb + n] = 0;
                            Hin[(size_t)m * Hn + n] = 0.0f;
                        }
                    }
                }
            }
    } else {  // PHASE 4 (sorted prefix)
#pragma unroll
        for (int fm = 0; fm < 2; fm++)
#pragma unroll
            for (int r = 0; r < 4; r++) {
                int s = m0 + wm * 32 + fm * 16 + (lane >> 4) * 4 + r;
                int alive = (s < cnt);
                int m = perm[s];
                int cch = m >> 3, bb = m & 7;
                int t = cch * Cn + j;
                size_t ob = ((size_t)bb * Tn + t) * (size_t)Hn;
                size_t sb = (size_t)s * Hn;
#pragma unroll
                for (int fn = 0; fn < 2; fn++) {
                    int n = n0 + wn * 32 + fn * 16 + (lane & 15);
                    if (alive) {
                        float val = acc[fm][fn][r];
                        unsigned short h1, h2;
                        split2f(val, h1, h2);
                        O0[sb + n] = h1; O1[sb + n] = h2;
                        Out[ob + n] += val;
                    }
                }
            }
    }
}

// ---------------------------------------------------------------------------
// Exact fallback for uncut chunks (E[occurrences] ~ 0.016).
// ---------------------------------------------------------------------------
__global__ __launch_bounds__(1024) void k_fallback(float* __restrict__ Hin,
                                                   const float* __restrict__ A,
                                                   const int* __restrict__ cut,
                                                   const int* __restrict__ anyUncut,
                                                   unsigned short* __restrict__ u1,
                                                   unsigned short* __restrict__ u2,
                                                   const int* __restrict__ iperm) {
    if (*anyUncut == 0) return;
    __shared__ float v0[Hn];
    __shared__ float v1[Hn];
    for (int c = 1; c < NCn; c++) {
        for (int b = 0; b < Bn; b++) {
            if (cut[(c - 1) * Bn + b]) continue;
            for (int n = threadIdx.x; n < Hn; n += 1024)
                v0[n] = Hin[((size_t)(c - 1) * Bn + b) * Hn + n];
            __syncthreads();
            for (int s = 0; s < Cn; s++) {
                float* pin = (s & 1) ? v1 : v0;
                float* pout = (s & 1) ? v0 : v1;
                for (int n = threadIdx.x; n < Hn; n += 1024) {
                    float accv = 0.0f;
                    const float* Ar = &A[(size_t)n * Hn];
                    for (int k = 0; k < Hn; k++) accv += pin[k] * Ar[k];
                    pout[n] = accv;
                }
                __syncthreads();
            }
            float* pres = (Cn & 1) ? v1 : v0;
            int mrow = c * Bn + b;
            size_t dst = (size_t)mrow * Hn;
            size_t sdst = (size_t)iperm[mrow] * Hn;
            for (int n = threadIdx.x; n < Hn; n += 1024) {
                float nv = Hin[dst + n] + pres[n];
                Hin[dst + n] = nv;
                unsigned short h1, h2;
                split2f(nv, h1, h2);
                u1[sdst + n] = h1; u2[sdst + n] = h2;
            }
            __syncthreads();
        }
    }
}

extern "C" void kernel_launch(void* const* d_in, const int* in_sizes, int n_in,
                              void* d_out, int out_size, void* d_ws, size_t ws_size,
                              hipStream_t stream) {
    const float* x = (const float*)d_in[0];
    const unsigned int* rst = (const unsigned int*)d_in[1];
    const float* Am = (const float*)d_in[2];
    const float* Bm = (const float*)d_in[3];
    float* Out = (float*)d_out;
    char* ws = (char*)d_ws;

    unsigned char* r8 = (unsigned char*)ws;                 // 16 KB
    int* cut = (int*)(ws + 16384);
    int* firstReset = (int*)(ws + 20480);
    int* perm = (int*)(ws + 24576);
    int* iperm = (int*)(ws + 28672);
    int* counts = (int*)(ws + 32768);
    int* anyUncut = (int*)(ws + 32832);
    unsigned short* a1 = (unsigned short*)(ws + 65536);     // A splits [n][k], 8MB ea
    unsigned short* a2 = a1 + 4194304;
    unsigned short* b1 = a2 + 4194304;                      // Bt splits [n][k], 8MB ea
    unsigned short* b2 = b1 + 4194304;
    unsigned short* sP1 = b2 + 4194304;                     // state splits, 4MB ea
    unsigned short* sP2 = sP1 + 2097152;
    unsigned short* sQ1 = sP2 + 2097152;
    unsigned short* sQ2 = sQ1 + 2097152;
    unsigned short* uP1 = sQ2 + 2097152;                    // carry u splits, 4MB ea
    unsigned short* uP2 = uP1 + 2097152;
    float* Hin = (float*)(uP2 + 2097152);                   // 8MB fp32
    unsigned short* x1 = (unsigned short*)(Hin + 2097152);  // X splits, 67MB ea
    unsigned short* x2 = x1 + 33554432;
    const size_t NEED_X = 201392128ull;
    const bool prex = (ws_size >= NEED_X);

    // Mega-prep: A/Bt splits + reset sort (+ X split when prex)
    int prep_grid = prex ? (5121 + 32768) : 5121;
    k_prep<<<prep_grid, 256, 0, stream>>>(Am, a1, a2, Bm, b1, b2,
                                          x, x1, x2, rst, r8, cut, firstReset,
                                          anyUncut, perm, iperm, counts);

    // Phase 1: bx = x @ B  (fused step0 -> sP)
    if (prex) {
        k_gemm_p1<1><<<dim3(Hn / 128, (Bn * Tn) / 256), 512, 0, stream>>>(
            x1, x2, b1, b2, nullptr, Out, sP1, sP2);
    } else {
        k_gemm_p1<0><<<dim3(Hn / 128, (Bn * Tn) / 256), 512, 0, stream>>>(
            nullptr, nullptr, b1, b2, x, Out, sP1, sP2);
    }

    // Phase 2: chunk-local scans (j=15 carries h_in into uP/Hin, zeroes c0)
    for (int j = 1; j < Cn; j++) {
        const unsigned short* i1 = (j & 1) ? sP1 : sQ1;
        const unsigned short* i2 = (j & 1) ? sP2 : sQ2;
        unsigned short* o1 = (j & 1) ? sQ1 : sP1;
        unsigned short* o2 = (j & 1) ? sQ2 : sP2;
        if (j < Cn - 1) {
            k_gemm_s<2><<<dim3(Hn / 64, M2n / 64), 256, 0, stream>>>(
                i1, i2, a1, a2, Out, o1, o2, r8, nullptr, nullptr, nullptr,
                nullptr, nullptr, nullptr, j);
        } else {
            k_gemm_s<3><<<dim3(Hn / 64, M2n / 64), 256, 0, stream>>>(
                i1, i2, a1, a2, Out, o1, o2, r8, nullptr, iperm, nullptr,
                uP1, uP2, Hin, j);
        }
    }

    // Phase 3: exact fallback for uncut chunks
    k_fallback<<<1, 1024, 0, stream>>>(Hin, Am, cut, anyUncut, uP1, uP2, iperm);

    // Phase 4: corrections on shrinking sorted prefix
    for (int j = 0; j < Cn; j++) {
        const unsigned short* i1 = (j == 0) ? uP1 : ((j & 1) ? sP1 : sQ1);
        const unsigned short* i2 = (j == 0) ? uP2 : ((j & 1) ? sP2 : sQ2);
        unsigned short* o1 = (j & 1) ? sQ1 : sP1;
        unsigned short* o2 = (j & 1) ? sQ2 : sP2;
        k_gemm_s<4><<<dim3(Hn / 64, M2n / 64), 256, 0, stream>>>(
            i1, i2, a1, a2, Out, o1, o2, nullptr, perm, nullptr, counts,
            nullptr, nullptr, nullptr, j);
    }
}

// Round 14
// 1966.247 us; speedup vs baseline: 1.0403x; 1.0403x over previous
//
#include <hip/hip_runtime.h>

#define Hn 2048
#define Bn 8
#define Tn 2048
#define Cn 16
#define NCn (Tn / Cn)     // 128 chunks
#define M2n (NCn * Bn)    // 1024 scan rows

using f32x4 = __attribute__((ext_vector_type(4))) float;
using u32x4 = __attribute__((ext_vector_type(4))) unsigned int;
using us4   = __attribute__((ext_vector_type(4))) unsigned short;
using bf8   = __attribute__((ext_vector_type(8))) short;
using f4    = __attribute__((ext_vector_type(4))) float;

#define GLOAD16(g, l) __builtin_amdgcn_global_load_lds(                      \
    (const __attribute__((address_space(1))) void*)(g),                      \
    (__attribute__((address_space(3))) void*)(l), 16, 0, 0)

__device__ __forceinline__ unsigned short f2bf(float f) {
    unsigned u = __builtin_bit_cast(unsigned, f);
    u = u + 0x7fffu + ((u >> 16) & 1u);
    return (unsigned short)(u >> 16);
}
__device__ __forceinline__ float bf2f(unsigned short h) {
    unsigned u = ((unsigned)h) << 16;
    return __builtin_bit_cast(float, u);
}
__device__ __forceinline__ void split2f(float v, unsigned short& a, unsigned short& b) {
    a = f2bf(v);
    b = f2bf(v - bf2f(a));
}

// ---------------------------------------------------------------------------
// Mega-prep kernel (single launch, block-range dispatch):
//  [0, 4096)            : A 2-way split
//  [4096, 5120)         : B^T 2-way split (transpose)
//  [5120]               : reset canonicalize + counting sort
//  [5121, 5121+32768)   : X 2-way split (only when prex grid launched)
// ---------------------------------------------------------------------------
__global__ __launch_bounds__(256) void k_prep(const float* __restrict__ A,
                                              unsigned short* __restrict__ a1,
                                              unsigned short* __restrict__ a2,
                                              const float* __restrict__ Bm,
                                              unsigned short* __restrict__ b1,
                                              unsigned short* __restrict__ b2,
                                              const float* __restrict__ X,
                                              unsigned short* __restrict__ x1,
                                              unsigned short* __restrict__ x2,
                                              const unsigned int* __restrict__ rin,
                                              unsigned char* __restrict__ r8,
                                              int* __restrict__ cut,
                                              int* __restrict__ firstReset,
                                              int* __restrict__ anyUncut,
                                              int* __restrict__ perm,
                                              int* __restrict__ iperm,
                                              int* __restrict__ counts) {
    const int bid = blockIdx.x;
    if (bid < 4096) {
        size_t i = ((size_t)bid * 256 + threadIdx.x) * 4;
        f32x4 v = *(const f32x4*)&A[i];
        us4 h1, h2;
#pragma unroll
        for (int e = 0; e < 4; e++) {
            unsigned short p, r;
            split2f(v[e], p, r);
            h1[e] = p; h2[e] = r;
        }
        *(us4*)&a1[i] = h1; *(us4*)&a2[i] = h2;
        return;
    }
    if (bid < 5120) {
        __shared__ float tile[64][65];
        int t = bid - 4096;
        const int k0 = (t >> 5) * 64, n0 = (t & 31) * 64;
        const int c = threadIdx.x & 63, r4 = threadIdx.x >> 6;
#pragma unroll
        for (int i = 0; i < 16; i++) {
            int r = r4 * 16 + i;
            tile[r][c] = Bm[(size_t)(k0 + r) * Hn + n0 + c];
        }
        __syncthreads();
#pragma unroll
        for (int i = 0; i < 16; i++) {
            int r = r4 * 16 + i;
            float v = tile[c][r];
            unsigned short p, q;
            split2f(v, p, q);
            b1[(size_t)(n0 + r) * Hn + k0 + c] = p;
            b2[(size_t)(n0 + r) * Hn + k0 + c] = q;
        }
        return;
    }
    if (bid == 5120) {
        __shared__ int s_badInt, s_badFloat;
        __shared__ int hist[17], off[18], cur[17];
        if (threadIdx.x == 0) { s_badInt = 0; s_badFloat = 0; *anyUncut = 0; }
        if (threadIdx.x < 17) hist[threadIdx.x] = 0;
        __syncthreads();
        int badI = 0, badF = 0;
        for (int i = threadIdx.x; i < 4096; i += 256) {
            unsigned int v = rin[i];
            if (v > 1u) badI = 1;
            if (v != 0u && v != 0x3f800000u) badF = 1;
        }
        if (badI) atomicOr(&s_badInt, 1);
        if (badF) atomicOr(&s_badFloat, 1);
        __syncthreads();
        const int fmt = (!s_badInt) ? 0 : ((!s_badFloat) ? 1 : 2);
        const unsigned char* rb = (const unsigned char*)rin;
        const float* rf = (const float*)rin;
        for (int i = threadIdx.x; i < Bn * Tn; i += 256) {
            unsigned char v;
            if (fmt == 0)      v = (unsigned char)(rin[i] != 0u);
            else if (fmt == 1) v = (unsigned char)(rf[i] != 0.0f);
            else               v = (unsigned char)(rb[i] != 0);
            r8[i] = v;
        }
        __syncthreads();
        int anyU = 0;
        for (int m = threadIdx.x; m < M2n; m += 256) {
            int c = m / Bn, b = m % Bn;
            int fr = Cn;
            for (int j = 0; j < Cn; j++) {
                if (r8[b * Tn + c * Cn + j]) { fr = j; break; }
            }
            firstReset[m] = fr;
            int ct = (fr < Cn);
            cut[m] = ct;
            if (!ct && c < NCn - 1) anyU = 1;
            atomicAdd(&hist[fr], 1);
        }
        if (anyU) atomicOr(anyUncut, 1);
        __syncthreads();
        if (threadIdx.x == 0) {
            off[16] = 0;
            for (int v = 15; v >= 0; v--) off[v] = off[v + 1] + hist[v + 1];
            for (int v = 0; v < 17; v++) cur[v] = (v == 16) ? 0 : off[v];
            for (int j = 0; j < 16; j++) counts[j] = off[j];
        }
        __syncthreads();
        for (int m = threadIdx.x; m < M2n; m += 256) {
            int fr = firstReset[m];
            int pos = atomicAdd(&cur[fr], 1);
            perm[pos] = m;
            iperm[m] = pos;
        }
        return;
    }
    {
        size_t i = ((size_t)(bid - 5121) * 256 + threadIdx.x) * 4;
        f32x4 v = *(const f32x4*)&X[i];
        us4 h1, h2;
#pragma unroll
        for (int e = 0; e < 4; e++) {
            unsigned short p, r;
            split2f(v[e], p, r);
            h1[e] = p; h2[e] = r;
        }
        *(us4*)&x1[i] = h1; *(us4*)&x2[i] = h2;
    }
}

// ---------------------------------------------------------------------------
// Phase-1 GEMM: Out[m,n] = sum_k X[m,k]*Bt[n,k], 3 products.
// 256x128 tile, 512 threads (8 waves, 4m x 2n), FM=FN=4, BK=32, granule
// swizzle (conflict-free), global_load_lds staging, simple 2-barrier loop
// (R6/R8-proven). 1D grid + XCD swizzle (T1): each m-panel's 16 n-blocks
// pin to one XCD -> X-panel fetched once per XCD (was 8x refetch).
// Fused step0 for t%16==0 rows.
// ---------------------------------------------------------------------------
template<int PREX>
__global__ __launch_bounds__(512) void k_gemm_p1(const unsigned short* __restrict__ X0,
                                                 const unsigned short* __restrict__ X1,
                                                 const unsigned short* __restrict__ B0,
                                                 const unsigned short* __restrict__ B1,
                                                 const float* __restrict__ Xf,
                                                 float* __restrict__ Out,
                                                 unsigned short* __restrict__ S0,
                                                 unsigned short* __restrict__ S1) {
    constexpr int BM = 256, BN = 128, LW = 32;
    __shared__ unsigned short ldsA[2 * BM * LW];   // 32 KB
    __shared__ unsigned short ldsB[2 * BN * LW];   // 16 KB
    const int tid = threadIdx.x;
    const int lane = tid & 63;
    const int wv = tid >> 6;
    const int wm = wv >> 1, wn = wv & 1;
    // XCD-aware decomposition of 1D grid (1024 = 64 m-panels x 16 n-panels)
    const int bid = blockIdx.x;
    const int xk = bid & 7, sq = bid >> 3;
    const int by = xk * 8 + (sq >> 4);
    const int bx = sq & 15;
    const int n0 = bx * BN;
    const int m0 = by * BM;

    f4 acc[4][4];
#pragma unroll
    for (int fm = 0; fm < 4; fm++)
#pragma unroll
        for (int fn = 0; fn < 4; fn++) acc[fm][fn] = (f4){0.f, 0.f, 0.f, 0.f};

    const unsigned short* gA[4];
    unsigned short* lA[4];
    const float* gX[2];
    unsigned short* lX[2];
    const unsigned short* gB[2];
    unsigned short* lB[2];
    if constexpr (PREX) {
#pragma unroll
        for (int q = 0; q < 4; q++) {
            int u = tid + q * 512;                 // 2048 granules (16B each)
            int sp = u >> 10, row = (u >> 2) & 255, slot = u & 3;
            int g = slot ^ ((row >> 1) & 3);       // swizzled source granule
            gA[q] = (sp ? X1 : X0) + (size_t)(m0 + row) * Hn + g * 8;
            lA[q] = &ldsA[u * 8];                  // linear LDS dest
        }
    } else {
#pragma unroll
        for (int q = 0; q < 2; q++) {
            int u = tid + q * 512;                 // 1024 items (row x granule)
            int row = u >> 2, slot = u & 3;
            int s = slot ^ ((row >> 1) & 3);       // swizzled LDS slot
            gX[q] = Xf + (size_t)(m0 + row) * Hn + slot * 8;
            lX[q] = &ldsA[row * LW + s * 8];       // hi plane; lo at +BM*LW
        }
    }
#pragma unroll
    for (int q = 0; q < 2; q++) {
        int u = tid + q * 512;                     // 1024 granules
        int sp = u >> 9, row = (u >> 2) & 127, slot = u & 3;
        int g = slot ^ ((row >> 1) & 3);
        gB[q] = (sp ? B1 : B0) + (size_t)(n0 + row) * Hn + g * 8;
        lB[q] = &ldsB[u * 8];
    }
    const int sl = (lane >> 4) ^ ((lane >> 1) & 3);   // read-side slot per lane
    const int pa[3] = {0, 0, 1};
    const int pb[3] = {0, 1, 0};

    for (int k0 = 0; k0 < Hn; k0 += 32) {
        if constexpr (PREX) {
#pragma unroll
            for (int q = 0; q < 4; q++) {
                GLOAD16(gA[q], lA[q]);
                gA[q] += 32;
            }
        } else {
#pragma unroll
            for (int q = 0; q < 2; q++) {
                f32x4 va = *(const f32x4*)gX[q];
                f32x4 vb = *(const f32x4*)(gX[q] + 4);
                gX[q] += 32;
                us4 h1a, h2a, h1b, h2b;
#pragma unroll
                for (int e = 0; e < 4; e++) {
                    unsigned short p, r;
                    split2f(va[e], p, r); h1a[e] = p; h2a[e] = r;
                    split2f(vb[e], p, r); h1b[e] = p; h2b[e] = r;
                }
                *(us4*)lX[q] = h1a;
                *(us4*)(lX[q] + 4) = h1b;
                *(us4*)(lX[q] + BM * LW) = h2a;
                *(us4*)(lX[q] + BM * LW + 4) = h2b;
            }
        }
#pragma unroll
        for (int q = 0; q < 2; q++) {
            GLOAD16(gB[q], lB[q]);
            gB[q] += 32;
        }
        __syncthreads();   // drains vmcnt(0): DMA staging complete

        bf8 af[2][4], bfr[2][4];
#pragma unroll
        for (int sp = 0; sp < 2; sp++)
#pragma unroll
            for (int f = 0; f < 4; f++)
                af[sp][f] = *(const bf8*)&ldsA[(sp * BM + wm * 64 + f * 16 + (lane & 15)) * LW + sl * 8];
#pragma unroll
        for (int sp = 0; sp < 2; sp++)
#pragma unroll
            for (int f = 0; f < 4; f++)
                bfr[sp][f] = *(const bf8*)&ldsB[(sp * BN + wn * 64 + f * 16 + (lane & 15)) * LW + sl * 8];

#pragma unroll
        for (int p = 0; p < 3; p++)
#pragma unroll
            for (int fm = 0; fm < 4; fm++)
#pragma unroll
                for (int fn = 0; fn < 4; fn++)
                    acc[fm][fn] = __builtin_amdgcn_mfma_f32_16x16x32_bf16(
                        af[pa[p]][fm], bfr[pb[p]][fn], acc[fm][fn], 0, 0, 0);
        __syncthreads();   // protect LDS reuse before next stage
    }

    // D mapping: row=(lane>>4)*4+r, col=lane&15. Fused step0 for t%16==0 rows.
#pragma unroll
    for (int fm = 0; fm < 4; fm++)
#pragma unroll
        for (int r = 0; r < 4; r++) {
            int row = m0 + wm * 64 + fm * 16 + (lane >> 4) * 4 + r;
            int bb = row >> 11, t = row & 2047;
            int isC0 = ((t & 15) == 0);
            size_t ob = (size_t)row * Hn;
            size_t sb = (size_t)((t >> 4) * 8 + bb) * Hn;
#pragma unroll
            for (int fn = 0; fn < 4; fn++) {
                int n = n0 + wn * 64 + fn * 16 + (lane & 15);
                float v = acc[fm][fn][r];
                Out[ob + n] = v;
                if (isC0) {
                    unsigned short h1, h2;
                    split2f(v, h1, h2);
                    S0[sb + n] = h1; S1[sb + n] = h2;
                }
            }
        }
}

// ---------------------------------------------------------------------------
// Scan / correction GEMM: 64x64 tile, 256 threads (2x2 waves), FM=FN=2, BK=64.
// A-operand (state rows, wave-private): direct global->register b128 loads
// PREFETCHED ONE K-TILE AHEAD. B-operand (shared weight panel): gload_lds +
// granule swizzle + 2-deep double-buffered pipeline. vmcnt(12) keeps exactly
// {B(t+1) stage (4) + A(t+1) prefetch (8)} in flight, retiring B(t)+A(t).
// R12 BUG FIXED: epilogue now prefetches A(NT-1) (was using stale A(NT-3)).
// LDS 32 KB; grid 512 = 2 blocks/CU.
// PHASE 2: v=(reset?0:acc)+Out; Out=v; split2 -> state.
// PHASE 3: as PHASE 2 (j=15) + carry u at iperm[m+8] + Hin[m+8]; zeroes
//          chunk-0 carry rows (m<8) inline.
// PHASE 4: correction on sorted alive prefix.
// ---------------------------------------------------------------------------
template<int PHASE>
__global__ __launch_bounds__(256) void k_gemm_s(const unsigned short* __restrict__ S0,
                                                const unsigned short* __restrict__ S1,
                                                const unsigned short* __restrict__ W0,
                                                const unsigned short* __restrict__ W1,
                                                float* __restrict__ Out,
                                                unsigned short* __restrict__ O0,
                                                unsigned short* __restrict__ O1,
                                                const unsigned char* __restrict__ r8v,
                                                const int* __restrict__ perm,
                                                const int* __restrict__ iperm,
                                                const int* __restrict__ counts,
                                                unsigned short* __restrict__ U0,
                                                unsigned short* __restrict__ U1,
                                                float* __restrict__ Hin,
                                                int j) {
    constexpr int BM = 64, BN = 64, BK = 64;
    constexpr int TSZ = 2 * BN * BK;               // 8192 shorts per B buffer
    constexpr int NT = Hn / BK;                    // 32 k-tiles
    __shared__ unsigned short ldsB[2 * TSZ];       // 32 KB (2 bufs)
    const int tid = threadIdx.x;
    const int lane = tid & 63;
    const int wv = tid >> 6;
    const int wm = wv >> 1, wn = wv & 1;
    const int n0 = blockIdx.x * BN;
    const int m0 = blockIdx.y * BM;

    int cnt = 0;
    if constexpr (PHASE == 4) {
        cnt = counts[j];
        if (m0 >= cnt) return;
    }

    f4 acc[2][2];
#pragma unroll
    for (int fm = 0; fm < 2; fm++)
#pragma unroll
        for (int fn = 0; fn < 2; fn++) acc[fm][fn] = (f4){0.f, 0.f, 0.f, 0.f};

    // B staging (4 gload_lds per stage)
    const unsigned short* gB[4];
    unsigned short* lB[4];
#pragma unroll
    for (int q = 0; q < 4; q++) {
        int u = tid + q * 256;                     // 1024 granules
        int sp = u >> 9, row = (u >> 3) & 63, s = u & 7;
        int g = s ^ (row & 7);                     // swizzled source granule
        gB[q] = (sp ? W1 : W0) + (size_t)(n0 + row) * Hn + g * 8;
        lB[q] = &ldsB[u * 8];
    }
    // A direct-load fragment pointers: [h][sp][f]
    const unsigned short* gAf[2][2][2];
#pragma unroll
    for (int h = 0; h < 2; h++)
#pragma unroll
        for (int sp = 0; sp < 2; sp++)
#pragma unroll
            for (int f = 0; f < 2; f++)
                gAf[h][sp][f] = (sp ? S1 : S0)
                    + (size_t)(m0 + wm * 32 + f * 16 + (lane & 15)) * Hn
                    + h * 32 + (lane >> 4) * 8;

    const int pa[3] = {0, 0, 1};
    const int pb[3] = {0, 1, 0};

#define STAGE_B(bsel)                                                        \
    {                                                                        \
        const int boff_ = (bsel) * TSZ;                                      \
        _Pragma("unroll")                                                    \
        for (int q = 0; q < 4; q++) {                                        \
            GLOAD16(gB[q], lB[q] + boff_);                                   \
            gB[q] += BK;                                                     \
        }                                                                    \
    }
#define LOADA(DST)                                                           \
    {                                                                        \
        _Pragma("unroll")                                                    \
        for (int h = 0; h < 2; h++)                                          \
            _Pragma("unroll")                                                \
            for (int sp = 0; sp < 2; sp++)                                   \
                _Pragma("unroll")                                            \
                for (int f = 0; f < 2; f++) {                                \
                    DST[h][sp][f] = *(const bf8*)gAf[h][sp][f];              \
                    gAf[h][sp][f] += BK;                                     \
                }                                                            \
    }
#define SBODY(t, CUR, NXT, PRE, VMN, STG)                                    \
    {                                                                        \
        if (PRE) LOADA(NXT);                                                 \
        asm volatile("s_waitcnt vmcnt(" VMN ")" ::: "memory");               \
        __builtin_amdgcn_sched_barrier(0);                                   \
        __builtin_amdgcn_s_barrier();                                        \
        const unsigned short* curB = &ldsB[((t) & 1) * TSZ];                 \
        bf8 bfr[2][2][2];                                                    \
        _Pragma("unroll")                                                    \
        for (int h = 0; h < 2; h++) {                                        \
            const int slh = ((h * 4) + (lane >> 4)) ^ (lane & 7);            \
            _Pragma("unroll")                                                \
            for (int sp = 0; sp < 2; sp++)                                   \
                _Pragma("unroll")                                            \
                for (int f = 0; f < 2; f++)                                  \
                    bfr[h][sp][f] = *(const bf8*)&curB[(sp * BN + wn * 32 + f * 16 + (lane & 15)) * BK + slh * 8]; \
        }                                                                    \
        asm volatile("s_waitcnt lgkmcnt(0)" ::: "memory");                   \
        __builtin_amdgcn_sched_barrier(0);                                   \
        __builtin_amdgcn_s_barrier();                                        \
        if (STG) STAGE_B((t) & 1);                                           \
        __builtin_amdgcn_sched_barrier(0);                                   \
        __builtin_amdgcn_s_setprio(1);                                       \
        _Pragma("unroll")                                                    \
        for (int h = 0; h < 2; h++)                                          \
            _Pragma("unroll")                                                \
            for (int p = 0; p < 3; p++)                                      \
                _Pragma("unroll")                                            \
                for (int fm = 0; fm < 2; fm++)                               \
                    _Pragma("unroll")                                        \
                    for (int fn = 0; fn < 2; fn++)                           \
                        acc[fm][fn] = __builtin_amdgcn_mfma_f32_16x16x32_bf16( \
                            CUR[h][pa[p]][fm], bfr[h][pb[p]][fn], acc[fm][fn], 0, 0, 0); \
        __builtin_amdgcn_s_setprio(0);                                       \
    }

    bf8 aP[2][2][2], aQ[2][2][2];
    // prologue: stage B tiles 0,1; prefetch A tile 0
    STAGE_B(0);
    STAGE_B(1);
    LOADA(aP);

    for (int t = 0; t < NT - 2; t += 2) {
        SBODY(t,     aP, aQ, 1, "12", (t + 2 < NT));
        SBODY(t + 1, aQ, aP, 1, "12", (t + 3 < NT));
    }
    // Epilogue (R12 fix): prefetch A(NT-1) into aQ; vmcnt(12) retires
    // B(NT-2)+A(NT-2), leaving exactly {B(NT-1), A(NT-1)} in flight.
    SBODY(NT - 2, aP, aQ, 1, "12", 0);
    SBODY(NT - 1, aQ, aP, 0, "0", 0);
#undef SBODY
#undef LOADA
#undef STAGE_B

    if constexpr (PHASE == 2 || PHASE == 3) {
#pragma unroll
        for (int fm = 0; fm < 2; fm++)
#pragma unroll
            for (int r = 0; r < 4; r++) {
                int m = m0 + wm * 32 + fm * 16 + (lane >> 4) * 4 + r;
                int cch = m >> 3, bb = m & 7;
                int t = cch * Cn + j;
                int rfl = r8v[bb * Tn + t];
                size_t ob = ((size_t)bb * Tn + t) * (size_t)Hn;
                size_t sb = (size_t)m * Hn;
                int carry = 0;
                size_t ub = 0, hb = 0;
                if constexpr (PHASE == 3) {
                    carry = (m < M2n - 8);
                    if (carry) {
                        ub = (size_t)iperm[m + 8] * Hn;
                        hb = (size_t)(m + 8) * Hn;
                    }
                }
#pragma unroll
                for (int fn = 0; fn < 2; fn++) {
                    int n = n0 + wn * 32 + fn * 16 + (lane & 15);
                    float v = (rfl ? 0.0f : acc[fm][fn][r]) + Out[ob + n];
                    Out[ob + n] = v;
                    unsigned short h1, h2;
                    split2f(v, h1, h2);
                    O0[sb + n] = h1; O1[sb + n] = h2;
                    if constexpr (PHASE == 3) {
                        if (carry) {
                            U0[ub + n] = h1; U1[ub + n] = h2;
                            Hin[hb + n] = v;
                        }
                        if (m < 8) {                       // chunk-0 carry = 0
                            size_t zb = (size_t)iperm[m] * Hn;
                            U0[zb + n] = 0; U1[zb + n] = 0;
                            Hin[(size_t)m * Hn + n] = 0.0f;
                        }
                    }
                }
            }
    } else {  // PHASE 4 (sorted prefix)
#pragma unroll
        for (int fm = 0; fm < 2; fm++)
#pragma unroll
            for (int r = 0; r < 4; r++) {
                int s = m0 + wm * 32 + fm * 16 + (lane >> 4) * 4 + r;
                int alive = (s < cnt);
                int m = perm[s];
                int cch = m >> 3, bb = m & 7;
                int t = cch * Cn + j;
                size_t ob = ((size_t)bb * Tn + t) * (size_t)Hn;
                size_t sb = (size_t)s * Hn;
#pragma unroll
                for (int fn = 0; fn < 2; fn++) {
                    int n = n0 + wn * 32 + fn * 16 + (lane & 15);
                    if (alive) {
                        float val = acc[fm][fn][r];
                        unsigned short h1, h2;
                        split2f(val, h1, h2);
                        O0[sb + n] = h1; O1[sb + n] = h2;
                        Out[ob + n] += val;
                    }
                }
            }
    }
}

// ---------------------------------------------------------------------------
// Exact fallback for uncut chunks (E[occurrences] ~ 0.016).
// ---------------------------------------------------------------------------
__global__ __launch_bounds__(1024) void k_fallback(float* __restrict__ Hin,
                                                   const float* __restrict__ A,
                                                   const int* __restrict__ cut,
                                                   const int* __restrict__ anyUncut,
                                                   unsigned short* __restrict__ u1,
                                                   unsigned short* __restrict__ u2,
                                                   const int* __restrict__ iperm) {
    if (*anyUncut == 0) return;
    __shared__ float v0[Hn];
    __shared__ float v1[Hn];
    for (int c = 1; c < NCn; c++) {
        for (int b = 0; b < Bn; b++) {
            if (cut[(c - 1) * Bn + b]) continue;
            for (int n = threadIdx.x; n < Hn; n += 1024)
                v0[n] = Hin[((size_t)(c - 1) * Bn + b) * Hn + n];
            __syncthreads();
            for (int s = 0; s < Cn; s++) {
                float* pin = (s & 1) ? v1 : v0;
                float* pout = (s & 1) ? v0 : v1;
                for (int n = threadIdx.x; n < Hn; n += 1024) {
                    float accv = 0.0f;
                    const float* Ar = &A[(size_t)n * Hn];
                    for (int k = 0; k < Hn; k++) accv += pin[k] * Ar[k];
                    pout[n] = accv;
                }
                __syncthreads();
            }
            float* pres = (Cn & 1) ? v1 : v0;
            int mrow = c * Bn + b;
            size_t dst = (size_t)mrow * Hn;
            size_t sdst = (size_t)iperm[mrow] * Hn;
            for (int n = threadIdx.x; n < Hn; n += 1024) {
                float nv = Hin[dst + n] + pres[n];
                Hin[dst + n] = nv;
                unsigned short h1, h2;
                split2f(nv, h1, h2);
                u1[sdst + n] = h1; u2[sdst + n] = h2;
            }
            __syncthreads();
        }
    }
}

extern "C" void kernel_launch(void* const* d_in, const int* in_sizes, int n_in,
                              void* d_out, int out_size, void* d_ws, size_t ws_size,
                              hipStream_t stream) {
    const float* x = (const float*)d_in[0];
    const unsigned int* rst = (const unsigned int*)d_in[1];
    const float* Am = (const float*)d_in[2];
    const float* Bm = (const float*)d_in[3];
    float* Out = (float*)d_out;
    char* ws = (char*)d_ws;

    unsigned char* r8 = (unsigned char*)ws;                 // 16 KB
    int* cut = (int*)(ws + 16384);
    int* firstReset = (int*)(ws + 20480);
    int* perm = (int*)(ws + 24576);
    int* iperm = (int*)(ws + 28672);
    int* counts = (int*)(ws + 32768);
    int* anyUncut = (int*)(ws + 32832);
    unsigned short* a1 = (unsigned short*)(ws + 65536);     // A splits [n][k], 8MB ea
    unsigned short* a2 = a1 + 4194304;
    unsigned short* b1 = a2 + 4194304;                      // Bt splits [n][k], 8MB ea
    unsigned short* b2 = b1 + 4194304;
    unsigned short* sP1 = b2 + 4194304;                     // state splits, 4MB ea
    unsigned short* sP2 = sP1 + 2097152;
    unsigned short* sQ1 = sP2 + 2097152;
    unsigned short* sQ2 = sQ1 + 2097152;
    unsigned short* uP1 = sQ2 + 2097152;                    // carry u splits, 4MB ea
    unsigned short* uP2 = uP1 + 2097152;
    float* Hin = (float*)(uP2 + 2097152);                   // 8MB fp32
    unsigned short* x1 = (unsigned short*)(Hin + 2097152);  // X splits, 67MB ea
    unsigned short* x2 = x1 + 33554432;
    const size_t NEED_X = 201392128ull;
    const bool prex = (ws_size >= NEED_X);

    // Mega-prep: A/Bt splits + reset sort (+ X split when prex)
    int prep_grid = prex ? (5121 + 32768) : 5121;
    k_prep<<<prep_grid, 256, 0, stream>>>(Am, a1, a2, Bm, b1, b2,
                                          x, x1, x2, rst, r8, cut, firstReset,
                                          anyUncut, perm, iperm, counts);

    // Phase 1: bx = x @ B  (fused step0 -> sP), 1D grid with XCD swizzle
    if (prex) {
        k_gemm_p1<1><<<1024, 512, 0, stream>>>(
            x1, x2, b1, b2, nullptr, Out, sP1, sP2);
    } else {
        k_gemm_p1<0><<<1024, 512, 0, stream>>>(
            nullptr, nullptr, b1, b2, x, Out, sP1, sP2);
    }

    // Phase 2: chunk-local scans (j=15 carries h_in into uP/Hin, zeroes c0)
    for (int j = 1; j < Cn; j++) {
        const unsigned short* i1 = (j & 1) ? sP1 : sQ1;
        const unsigned short* i2 = (j & 1) ? sP2 : sQ2;
        unsigned short* o1 = (j & 1) ? sQ1 : sP1;
        unsigned short* o2 = (j & 1) ? sQ2 : sP2;
        if (j < Cn - 1) {
            k_gemm_s<2><<<dim3(Hn / 64, M2n / 64), 256, 0, stream>>>(
                i1, i2, a1, a2, Out, o1, o2, r8, nullptr, nullptr, nullptr,
                nullptr, nullptr, nullptr, j);
        } else {
            k_gemm_s<3><<<dim3(Hn / 64, M2n / 64), 256, 0, stream>>>(
                i1, i2, a1, a2, Out, o1, o2, r8, nullptr, iperm, nullptr,
                uP1, uP2, Hin, j);
        }
    }

    // Phase 3: exact fallback for uncut chunks
    k_fallback<<<1, 1024, 0, stream>>>(Hin, Am, cut, anyUncut, uP1, uP2, iperm);

    // Phase 4: corrections on shrinking sorted prefix
    for (int j = 0; j < Cn; j++) {
        const unsigned short* i1 = (j == 0) ? uP1 : ((j & 1) ? sP1 : sQ1);
        const unsigned short* i2 = (j == 0) ? uP2 : ((j & 1) ? sP2 : sQ2);
        unsigned short* o1 = (j & 1) ? sQ1 : sP1;
        unsigned short* o2 = (j & 1) ? sQ2 : sP2;
        k_gemm_s<4><<<dim3(Hn / 64, M2n / 64), 256, 0, stream>>>(
            i1, i2, a1, a2, Out, o1, o2, nullptr, perm, nullptr, counts,
            nullptr, nullptr, nullptr, j);
    }
}

// Round 15
// 1234.409 us; speedup vs baseline: 1.6571x; 1.5929x over previous
//
#include <hip/hip_runtime.h>

#define Hn 2048
#define Bn 8
#define Tn 2048
#define Cn 16
#define NCn (Tn / Cn)     // 128 chunks
#define M2n (NCn * Bn)    // 1024 scan rows

using f32x4 = __attribute__((ext_vector_type(4))) float;
using u32x4 = __attribute__((ext_vector_type(4))) unsigned int;
using us4   = __attribute__((ext_vector_type(4))) unsigned short;
using bf8   = __attribute__((ext_vector_type(8))) short;
using f4    = __attribute__((ext_vector_type(4))) float;

#define GLOAD16(g, l) __builtin_amdgcn_global_load_lds(                      \
    (const __attribute__((address_space(1))) void*)(g),                      \
    (__attribute__((address_space(3))) void*)(l), 16, 0, 0)

__device__ __forceinline__ unsigned short f2bf(float f) {
    unsigned u = __builtin_bit_cast(unsigned, f);
    u = u + 0x7fffu + ((u >> 16) & 1u);
    return (unsigned short)(u >> 16);
}
__device__ __forceinline__ float bf2f(unsigned short h) {
    unsigned u = ((unsigned)h) << 16;
    return __builtin_bit_cast(float, u);
}
__device__ __forceinline__ void split2f(float v, unsigned short& a, unsigned short& b) {
    a = f2bf(v);
    b = f2bf(v - bf2f(a));
}

// ---------------------------------------------------------------------------
// Mega-prep kernel (single launch, block-range dispatch):
//  [0, 4096)            : A 2-way split
//  [4096, 5120)         : B^T 2-way split (transpose)
//  [5120]               : reset canonicalize + counting sort
//  [5121, 5121+32768)   : X 2-way split (only when prex grid launched)
// ---------------------------------------------------------------------------
__global__ __launch_bounds__(256) void k_prep(const float* __restrict__ A,
                                              unsigned short* __restrict__ a1,
                                              unsigned short* __restrict__ a2,
                                              const float* __restrict__ Bm,
                                              unsigned short* __restrict__ b1,
                                              unsigned short* __restrict__ b2,
                                              const float* __restrict__ X,
                                              unsigned short* __restrict__ x1,
                                              unsigned short* __restrict__ x2,
                                              const unsigned int* __restrict__ rin,
                                              unsigned char* __restrict__ r8,
                                              int* __restrict__ cut,
                                              int* __restrict__ firstReset,
                                              int* __restrict__ anyUncut,
                                              int* __restrict__ perm,
                                              int* __restrict__ iperm,
                                              int* __restrict__ counts) {
    const int bid = blockIdx.x;
    if (bid < 4096) {
        // ---- A split ----
        size_t i = ((size_t)bid * 256 + threadIdx.x) * 4;
        f32x4 v = *(const f32x4*)&A[i];
        us4 h1, h2;
#pragma unroll
        for (int e = 0; e < 4; e++) {
            unsigned short p, r;
            split2f(v[e], p, r);
            h1[e] = p; h2[e] = r;
        }
        *(us4*)&a1[i] = h1; *(us4*)&a2[i] = h2;
        return;
    }
    if (bid < 5120) {
        // ---- B^T split ----
        __shared__ float tile[64][65];
        int t = bid - 4096;
        const int k0 = (t >> 5) * 64, n0 = (t & 31) * 64;
        const int c = threadIdx.x & 63, r4 = threadIdx.x >> 6;
#pragma unroll
        for (int i = 0; i < 16; i++) {
            int r = r4 * 16 + i;
            tile[r][c] = Bm[(size_t)(k0 + r) * Hn + n0 + c];
        }
        __syncthreads();
#pragma unroll
        for (int i = 0; i < 16; i++) {
            int r = r4 * 16 + i;
            float v = tile[c][r];
            unsigned short p, q;
            split2f(v, p, q);
            b1[(size_t)(n0 + r) * Hn + k0 + c] = p;
            b2[(size_t)(n0 + r) * Hn + k0 + c] = q;
        }
        return;
    }
    if (bid == 5120) {
        // ---- reset prep ----
        __shared__ int s_badInt, s_badFloat;
        __shared__ int hist[17], off[18], cur[17];
        if (threadIdx.x == 0) { s_badInt = 0; s_badFloat = 0; *anyUncut = 0; }
        if (threadIdx.x < 17) hist[threadIdx.x] = 0;
        __syncthreads();
        int badI = 0, badF = 0;
        for (int i = threadIdx.x; i < 4096; i += 256) {
            unsigned int v = rin[i];
            if (v > 1u) badI = 1;
            if (v != 0u && v != 0x3f800000u) badF = 1;
        }
        if (badI) atomicOr(&s_badInt, 1);
        if (badF) atomicOr(&s_badFloat, 1);
        __syncthreads();
        const int fmt = (!s_badInt) ? 0 : ((!s_badFloat) ? 1 : 2);
        const unsigned char* rb = (const unsigned char*)rin;
        const float* rf = (const float*)rin;
        for (int i = threadIdx.x; i < Bn * Tn; i += 256) {
            unsigned char v;
            if (fmt == 0)      v = (unsigned char)(rin[i] != 0u);
            else if (fmt == 1) v = (unsigned char)(rf[i] != 0.0f);
            else               v = (unsigned char)(rb[i] != 0);
            r8[i] = v;
        }
        __syncthreads();
        int anyU = 0;
        for (int m = threadIdx.x; m < M2n; m += 256) {
            int c = m / Bn, b = m % Bn;
            int fr = Cn;
            for (int j = 0; j < Cn; j++) {
                if (r8[b * Tn + c * Cn + j]) { fr = j; break; }
            }
            firstReset[m] = fr;
            int ct = (fr < Cn);
            cut[m] = ct;
            if (!ct && c < NCn - 1) anyU = 1;
            atomicAdd(&hist[fr], 1);
        }
        if (anyU) atomicOr(anyUncut, 1);
        __syncthreads();
        if (threadIdx.x == 0) {
            off[16] = 0;
            for (int v = 15; v >= 0; v--) off[v] = off[v + 1] + hist[v + 1];
            for (int v = 0; v < 17; v++) cur[v] = (v == 16) ? 0 : off[v];
            for (int j = 0; j < 16; j++) counts[j] = off[j];
        }
        __syncthreads();
        for (int m = threadIdx.x; m < M2n; m += 256) {
            int fr = firstReset[m];
            int pos = atomicAdd(&cur[fr], 1);
            perm[pos] = m;
            iperm[m] = pos;
        }
        return;
    }
    // ---- X split ----
    {
        size_t i = ((size_t)(bid - 5121) * 256 + threadIdx.x) * 4;
        f32x4 v = *(const f32x4*)&X[i];
        us4 h1, h2;
#pragma unroll
        for (int e = 0; e < 4; e++) {
            unsigned short p, r;
            split2f(v[e], p, r);
            h1[e] = p; h2[e] = r;
        }
        *(us4*)&x1[i] = h1; *(us4*)&x2[i] = h2;
    }
}

// ---------------------------------------------------------------------------
// Phase-1 GEMM: Out[m,n] = sum_k X[m,k]*Bt[n,k], 3 products.
// 256x128 tile, 512 threads (8 waves, 4m x 2n), FM=FN=4, BK=32, granule
// swizzle (conflict-free), global_load_lds staging, simple 2-barrier loop.
// 2D grid (default dispatch — measured better than XCD swizzle here).
// Fused step0 for t%16==0 rows.
// ---------------------------------------------------------------------------
template<int PREX>
__global__ __launch_bounds__(512) void k_gemm_p1(const unsigned short* __restrict__ X0,
                                                 const unsigned short* __restrict__ X1,
                                                 const unsigned short* __restrict__ B0,
                                                 const unsigned short* __restrict__ B1,
                                                 const float* __restrict__ Xf,
                                                 float* __restrict__ Out,
                                                 unsigned short* __restrict__ S0,
                                                 unsigned short* __restrict__ S1) {
    constexpr int BM = 256, BN = 128, LW = 32;
    __shared__ unsigned short ldsA[2 * BM * LW];   // 32 KB
    __shared__ unsigned short ldsB[2 * BN * LW];   // 16 KB
    const int tid = threadIdx.x;
    const int lane = tid & 63;
    const int wv = tid >> 6;
    const int wm = wv >> 1, wn = wv & 1;
    const int n0 = blockIdx.x * BN;
    const int m0 = blockIdx.y * BM;

    f4 acc[4][4];
#pragma unroll
    for (int fm = 0; fm < 4; fm++)
#pragma unroll
        for (int fn = 0; fn < 4; fn++) acc[fm][fn] = (f4){0.f, 0.f, 0.f, 0.f};

    const unsigned short* gA[4];
    unsigned short* lA[4];
    const float* gX[2];
    unsigned short* lX[2];
    const unsigned short* gB[2];
    unsigned short* lB[2];
    if constexpr (PREX) {
#pragma unroll
        for (int q = 0; q < 4; q++) {
            int u = tid + q * 512;                 // 2048 granules (16B each)
            int sp = u >> 10, row = (u >> 2) & 255, slot = u & 3;
            int g = slot ^ ((row >> 1) & 3);       // swizzled source granule
            gA[q] = (sp ? X1 : X0) + (size_t)(m0 + row) * Hn + g * 8;
            lA[q] = &ldsA[u * 8];                  // linear LDS dest
        }
    } else {
#pragma unroll
        for (int q = 0; q < 2; q++) {
            int u = tid + q * 512;                 // 1024 items (row x granule)
            int row = u >> 2, slot = u & 3;
            int s = slot ^ ((row >> 1) & 3);       // swizzled LDS slot
            gX[q] = Xf + (size_t)(m0 + row) * Hn + slot * 8;
            lX[q] = &ldsA[row * LW + s * 8];       // hi plane; lo at +BM*LW
        }
    }
#pragma unroll
    for (int q = 0; q < 2; q++) {
        int u = tid + q * 512;                     // 1024 granules
        int sp = u >> 9, row = (u >> 2) & 127, slot = u & 3;
        int g = slot ^ ((row >> 1) & 3);
        gB[q] = (sp ? B1 : B0) + (size_t)(n0 + row) * Hn + g * 8;
        lB[q] = &ldsB[u * 8];
    }
    const int sl = (lane >> 4) ^ ((lane >> 1) & 3);   // read-side slot per lane
    const int pa[3] = {0, 0, 1};
    const int pb[3] = {0, 1, 0};

    for (int k0 = 0; k0 < Hn; k0 += 32) {
        if constexpr (PREX) {
#pragma unroll
            for (int q = 0; q < 4; q++) {
                GLOAD16(gA[q], lA[q]);
                gA[q] += 32;
            }
        } else {
#pragma unroll
            for (int q = 0; q < 2; q++) {
                f32x4 va = *(const f32x4*)gX[q];
                f32x4 vb = *(const f32x4*)(gX[q] + 4);
                gX[q] += 32;
                us4 h1a, h2a, h1b, h2b;
#pragma unroll
                for (int e = 0; e < 4; e++) {
                    unsigned short p, r;
                    split2f(va[e], p, r); h1a[e] = p; h2a[e] = r;
                    split2f(vb[e], p, r); h1b[e] = p; h2b[e] = r;
                }
                *(us4*)lX[q] = h1a;
                *(us4*)(lX[q] + 4) = h1b;
                *(us4*)(lX[q] + BM * LW) = h2a;
                *(us4*)(lX[q] + BM * LW + 4) = h2b;
            }
        }
#pragma unroll
        for (int q = 0; q < 2; q++) {
            GLOAD16(gB[q], lB[q]);
            gB[q] += 32;
        }
        __syncthreads();   // drains vmcnt(0): DMA staging complete

        bf8 af[2][4], bfr[2][4];
#pragma unroll
        for (int sp = 0; sp < 2; sp++)
#pragma unroll
            for (int f = 0; f < 4; f++)
                af[sp][f] = *(const bf8*)&ldsA[(sp * BM + wm * 64 + f * 16 + (lane & 15)) * LW + sl * 8];
#pragma unroll
        for (int sp = 0; sp < 2; sp++)
#pragma unroll
            for (int f = 0; f < 4; f++)
                bfr[sp][f] = *(const bf8*)&ldsB[(sp * BN + wn * 64 + f * 16 + (lane & 15)) * LW + sl * 8];

#pragma unroll
        for (int p = 0; p < 3; p++)
#pragma unroll
            for (int fm = 0; fm < 4; fm++)
#pragma unroll
                for (int fn = 0; fn < 4; fn++)
                    acc[fm][fn] = __builtin_amdgcn_mfma_f32_16x16x32_bf16(
                        af[pa[p]][fm], bfr[pb[p]][fn], acc[fm][fn], 0, 0, 0);
        __syncthreads();   // protect LDS reuse before next stage
    }

    // D mapping: row=(lane>>4)*4+r, col=lane&15. Fused step0 for t%16==0 rows.
#pragma unroll
    for (int fm = 0; fm < 4; fm++)
#pragma unroll
        for (int r = 0; r < 4; r++) {
            int row = m0 + wm * 64 + fm * 16 + (lane >> 4) * 4 + r;
            int bb = row >> 11, t = row & 2047;
            int isC0 = ((t & 15) == 0);
            size_t ob = (size_t)row * Hn;
            size_t sb = (size_t)((t >> 4) * 8 + bb) * Hn;
#pragma unroll
            for (int fn = 0; fn < 4; fn++) {
                int n = n0 + wn * 64 + fn * 16 + (lane & 15);
                float v = acc[fm][fn][r];
                Out[ob + n] = v;
                if (isC0) {
                    unsigned short h1, h2;
                    split2f(v, h1, h2);
                    S0[sb + n] = h1; S1[sb + n] = h2;
                }
            }
        }
}

// ---------------------------------------------------------------------------
// Scan / correction GEMM: 64x64 tile, 256 threads (2x2 waves), FM=FN=2,
// BK=64, granule swizzle, 2-deep double-buffered pipeline with counted
// vmcnt(8); s_setprio(1) around MFMA cluster (T5). All-LDS operand path
// (R8-proven best).
// PHASE 2: v=(reset?0:acc)+Out; Out=v; split2 -> state.
// PHASE 3: as PHASE 2 (j=15) + carry u at iperm[m+8] + Hin[m+8]; zeroes
//          chunk-0 carry rows (m<8) inline.
// PHASE 4: correction on sorted alive prefix.
// ---------------------------------------------------------------------------
template<int PHASE>
__global__ __launch_bounds__(256) void k_gemm_s(const unsigned short* __restrict__ S0,
                                                const unsigned short* __restrict__ S1,
                                                const unsigned short* __restrict__ W0,
                                                const unsigned short* __restrict__ W1,
                                                float* __restrict__ Out,
                                                unsigned short* __restrict__ O0,
                                                unsigned short* __restrict__ O1,
                                                const unsigned char* __restrict__ r8v,
                                                const int* __restrict__ perm,
                                                const int* __restrict__ iperm,
                                                const int* __restrict__ counts,
                                                unsigned short* __restrict__ U0,
                                                unsigned short* __restrict__ U1,
                                                float* __restrict__ Hin,
                                                int j) {
    constexpr int BM = 64, BN = 64, BK = 64;
    constexpr int TSZ = 2 * BM * BK;               // shorts per tile buffer (8192)
    constexpr int NT = Hn / BK;                    // 32 k-tiles
    __shared__ unsigned short ldsA[2 * TSZ];       // 32 KB (2 bufs)
    __shared__ unsigned short ldsB[2 * TSZ];       // 32 KB
    const int tid = threadIdx.x;
    const int lane = tid & 63;
    const int wv = tid >> 6;
    const int wm = wv >> 1, wn = wv & 1;
    const int n0 = blockIdx.x * BN;
    const int m0 = blockIdx.y * BM;

    int cnt = 0;
    if constexpr (PHASE == 4) {
        cnt = counts[j];
        if (m0 >= cnt) return;
    }

    f4 acc[2][2];
#pragma unroll
    for (int fm = 0; fm < 2; fm++)
#pragma unroll
        for (int fn = 0; fn < 2; fn++) acc[fm][fn] = (f4){0.f, 0.f, 0.f, 0.f};

    const unsigned short* gA[4];
    unsigned short* lA[4];
    const unsigned short* gB[4];
    unsigned short* lB[4];
#pragma unroll
    for (int q = 0; q < 4; q++) {
        int u = tid + q * 256;                     // 1024 granules per operand
        int sp = u >> 9, row = (u >> 3) & 63, s = u & 7;
        int g = s ^ (row & 7);                     // swizzled source granule
        gA[q] = (sp ? S1 : S0) + (size_t)(m0 + row) * Hn + g * 8;
        lA[q] = &ldsA[u * 8];
        gB[q] = (sp ? W1 : W0) + (size_t)(n0 + row) * Hn + g * 8;
        lB[q] = &ldsB[u * 8];
    }
    const int pa[3] = {0, 0, 1};
    const int pb[3] = {0, 1, 0};

#define STAGE_S(bsel)                                                        \
    {                                                                        \
        const int boff_ = (bsel) * TSZ;                                      \
        _Pragma("unroll")                                                    \
        for (int q = 0; q < 4; q++) {                                        \
            GLOAD16(gA[q], lA[q] + boff_);                                   \
            GLOAD16(gB[q], lB[q] + boff_);                                   \
            gA[q] += BK; gB[q] += BK;                                        \
        }                                                                    \
    }

    // prologue: stage tiles 0 and 1
    STAGE_S(0);
    STAGE_S(1);

    for (int t = 0; t < NT; t++) {
        if (t == NT - 1) { asm volatile("s_waitcnt vmcnt(0)" ::: "memory"); }
        else             { asm volatile("s_waitcnt vmcnt(8)" ::: "memory"); }
        __builtin_amdgcn_sched_barrier(0);
        __builtin_amdgcn_s_barrier();

        const unsigned short* curA = &ldsA[(t & 1) * TSZ];
        const unsigned short* curB = &ldsB[(t & 1) * TSZ];
        bf8 af[2][2][2], bfr[2][2][2];             // [h][sp][f]
#pragma unroll
        for (int h = 0; h < 2; h++) {
            const int slh = ((h * 4) + (lane >> 4)) ^ (lane & 7);
#pragma unroll
            for (int sp = 0; sp < 2; sp++)
#pragma unroll
                for (int f = 0; f < 2; f++) {
                    af[h][sp][f] = *(const bf8*)&curA[(sp * BM + wm * 32 + f * 16 + (lane & 15)) * BK + slh * 8];
                    bfr[h][sp][f] = *(const bf8*)&curB[(sp * BN + wn * 32 + f * 16 + (lane & 15)) * BK + slh * 8];
                }
        }
        asm volatile("s_waitcnt lgkmcnt(0)" ::: "memory");
        __builtin_amdgcn_sched_barrier(0);
        __builtin_amdgcn_s_barrier();

        if (t + 2 < NT) STAGE_S(t & 1);
        __builtin_amdgcn_sched_barrier(0);

        __builtin_amdgcn_s_setprio(1);
#pragma unroll
        for (int h = 0; h < 2; h++)
#pragma unroll
            for (int p = 0; p < 3; p++)
#pragma unroll
                for (int fm = 0; fm < 2; fm++)
#pragma unroll
                    for (int fn = 0; fn < 2; fn++)
                        acc[fm][fn] = __builtin_amdgcn_mfma_f32_16x16x32_bf16(
                            af[h][pa[p]][fm], bfr[h][pb[p]][fn], acc[fm][fn], 0, 0, 0);
        __builtin_amdgcn_s_setprio(0);
    }
#undef STAGE_S

    if constexpr (PHASE == 2 || PHASE == 3) {
#pragma unroll
        for (int fm = 0; fm < 2; fm++)
#pragma unroll
            for (int r = 0; r < 4; r++) {
                int m = m0 + wm * 32 + fm * 16 + (lane >> 4) * 4 + r;
                int cch = m >> 3, bb = m & 7;
                int t = cch * Cn + j;
                int rfl = r8v[bb * Tn + t];
                size_t ob = ((size_t)bb * Tn + t) * (size_t)Hn;
                size_t sb = (size_t)m * Hn;
                int carry = 0;
                size_t ub = 0, hb = 0;
                if constexpr (PHASE == 3) {
                    carry = (m < M2n - 8);
                    if (carry) {
                        ub = (size_t)iperm[m + 8] * Hn;
                        hb = (size_t)(m + 8) * Hn;
                    }
                }
#pragma unroll
                for (int fn = 0; fn < 2; fn++) {
                    int n = n0 + wn * 32 + fn * 16 + (lane & 15);
                    float v = (rfl ? 0.0f : acc[fm][fn][r]) + Out[ob + n];
                    Out[ob + n] = v;
                    unsigned short h1, h2;
                    split2f(v, h1, h2);
                    O0[sb + n] = h1; O1[sb + n] = h2;
                    if constexpr (PHASE == 3) {
                        if (carry) {
                            U0[ub + n] = h1; U1[ub + n] = h2;
                            Hin[hb + n] = v;
                        }
                        if (m < 8) {                       // chunk-0 carry = 0
                            size_t zb = (size_t)iperm[m] * Hn;
                            U0[zb + n] = 0; U1[zb + n] = 0;
                            Hin[(size_t)m * Hn + n] = 0.0f;
                        }
                    }
                }
            }
    } else {  // PHASE 4 (sorted prefix)
#pragma unroll
        for (int fm = 0; fm < 2; fm++)
#pragma unroll
            for (int r = 0; r < 4; r++) {
                int s = m0 + wm * 32 + fm * 16 + (lane >> 4) * 4 + r;
                int alive = (s < cnt);
                int m = perm[s];
                int cch = m >> 3, bb = m & 7;
                int t = cch * Cn + j;
                size_t ob = ((size_t)bb * Tn + t) * (size_t)Hn;
                size_t sb = (size_t)s * Hn;
#pragma unroll
                for (int fn = 0; fn < 2; fn++) {
                    int n = n0 + wn * 32 + fn * 16 + (lane & 15);
                    if (alive) {
                        float val = acc[fm][fn][r];
                        unsigned short h1, h2;
                        split2f(val, h1, h2);
                        O0[sb + n] = h1; O1[sb + n] = h2;
                        Out[ob + n] += val;
                    }
                }
            }
    }
}

// ---------------------------------------------------------------------------
// Exact fallback for uncut chunks (E[occurrences] ~ 0.016).
// ---------------------------------------------------------------------------
__global__ __launch_bounds__(1024) void k_fallback(float* __restrict__ Hin,
                                                   const float* __restrict__ A,
                                                   const int* __restrict__ cut,
                                                   const int* __restrict__ anyUncut,
                                                   unsigned short* __restrict__ u1,
                                                   unsigned short* __restrict__ u2,
                                                   const int* __restrict__ iperm) {
    if (*anyUncut == 0) return;
    __shared__ float v0[Hn];
    __shared__ float v1[Hn];
    for (int c = 1; c < NCn; c++) {
        for (int b = 0; b < Bn; b++) {
            if (cut[(c - 1) * Bn + b]) continue;
            for (int n = threadIdx.x; n < Hn; n += 1024)
                v0[n] = Hin[((size_t)(c - 1) * Bn + b) * Hn + n];
            __syncthreads();
            for (int s = 0; s < Cn; s++) {
                float* pin = (s & 1) ? v1 : v0;
                float* pout = (s & 1) ? v0 : v1;
                for (int n = threadIdx.x; n < Hn; n += 1024) {
                    float accv = 0.0f;
                    const float* Ar = &A[(size_t)n * Hn];
                    for (int k = 0; k < Hn; k++) accv += pin[k] * Ar[k];
                    pout[n] = accv;
                }
                __syncthreads();
            }
            float* pres = (Cn & 1) ? v1 : v0;
            int mrow = c * Bn + b;
            size_t dst = (size_t)mrow * Hn;
            size_t sdst = (size_t)iperm[mrow] * Hn;
            for (int n = threadIdx.x; n < Hn; n += 1024) {
                float nv = Hin[dst + n] + pres[n];
                Hin[dst + n] = nv;
                unsigned short h1, h2;
                split2f(nv, h1, h2);
                u1[sdst + n] = h1; u2[sdst + n] = h2;
            }
            __syncthreads();
        }
    }
}

extern "C" void kernel_launch(void* const* d_in, const int* in_sizes, int n_in,
                              void* d_out, int out_size, void* d_ws, size_t ws_size,
                              hipStream_t stream) {
    const float* x = (const float*)d_in[0];
    const unsigned int* rst = (const unsigned int*)d_in[1];
    const float* Am = (const float*)d_in[2];
    const float* Bm = (const float*)d_in[3];
    float* Out = (float*)d_out;
    char* ws = (char*)d_ws;

    unsigned char* r8 = (unsigned char*)ws;                 // 16 KB
    int* cut = (int*)(ws + 16384);
    int* firstReset = (int*)(ws + 20480);
    int* perm = (int*)(ws + 24576);
    int* iperm = (int*)(ws + 28672);
    int* counts = (int*)(ws + 32768);
    int* anyUncut = (int*)(ws + 32832);
    unsigned short* a1 = (unsigned short*)(ws + 65536);     // A splits [n][k], 8MB ea
    unsigned short* a2 = a1 + 4194304;
    unsigned short* b1 = a2 + 4194304;                      // Bt splits [n][k], 8MB ea
    unsigned short* b2 = b1 + 4194304;
    unsigned short* sP1 = b2 + 4194304;                     // state splits, 4MB ea
    unsigned short* sP2 = sP1 + 2097152;
    unsigned short* sQ1 = sP2 + 2097152;
    unsigned short* sQ2 = sQ1 + 2097152;
    unsigned short* uP1 = sQ2 + 2097152;                    // carry u splits, 4MB ea
    unsigned short* uP2 = uP1 + 2097152;
    float* Hin = (float*)(uP2 + 2097152);                   // 8MB fp32
    unsigned short* x1 = (unsigned short*)(Hin + 2097152);  // X splits, 67MB ea
    unsigned short* x2 = x1 + 33554432;
    const size_t NEED_X = 201392128ull;
    const bool prex = (ws_size >= NEED_X);

    // Mega-prep: A/Bt splits + reset sort (+ X split when prex)
    int prep_grid = prex ? (5121 + 32768) : 5121;
    k_prep<<<prep_grid, 256, 0, stream>>>(Am, a1, a2, Bm, b1, b2,
                                          x, x1, x2, rst, r8, cut, firstReset,
                                          anyUncut, perm, iperm, counts);

    // Phase 1: bx = x @ B  (fused step0 -> sP)
    if (prex) {
        k_gemm_p1<1><<<dim3(Hn / 128, (Bn * Tn) / 256), 512, 0, stream>>>(
            x1, x2, b1, b2, nullptr, Out, sP1, sP2);
    } else {
        k_gemm_p1<0><<<dim3(Hn / 128, (Bn * Tn) / 256), 512, 0, stream>>>(
            nullptr, nullptr, b1, b2, x, Out, sP1, sP2);
    }

    // Phase 2: chunk-local scans (j=15 carries h_in into uP/Hin, zeroes c0)
    for (int j = 1; j < Cn; j++) {
        const unsigned short* i1 = (j & 1) ? sP1 : sQ1;
        const unsigned short* i2 = (j & 1) ? sP2 : sQ2;
        unsigned short* o1 = (j & 1) ? sQ1 : sP1;
        unsigned short* o2 = (j & 1) ? sQ2 : sP2;
        if (j < Cn - 1) {
            k_gemm_s<2><<<dim3(Hn / 64, M2n / 64), 256, 0, stream>>>(
                i1, i2, a1, a2, Out, o1, o2, r8, nullptr, nullptr, nullptr,
                nullptr, nullptr, nullptr, j);
        } else {
            k_gemm_s<3><<<dim3(Hn / 64, M2n / 64), 256, 0, stream>>>(
                i1, i2, a1, a2, Out, o1, o2, r8, nullptr, iperm, nullptr,
                uP1, uP2, Hin, j);
        }
    }

    // Phase 3: exact fallback for uncut chunks
    k_fallback<<<1, 1024, 0, stream>>>(Hin, Am, cut, anyUncut, uP1, uP2, iperm);

    // Phase 4: corrections on shrinking sorted prefix
    for (int j = 0; j < Cn; j++) {
        const unsigned short* i1 = (j == 0) ? uP1 : ((j & 1) ? sP1 : sQ1);
        const unsigned short* i2 = (j == 0) ? uP2 : ((j & 1) ? sP2 : sQ2);
        unsigned short* o1 = (j & 1) ? sQ1 : sP1;
        unsigned short* o2 = (j & 1) ? sQ2 : sP2;
        k_gemm_s<4><<<dim3(Hn / 64, M2n / 64), 256, 0, stream>>>(
            i1, i2, a1, a2, Out, o1, o2, nullptr, perm, nullptr, counts,
            nullptr, nullptr, nullptr, j);
    }
}